// Round 3
// baseline (329.780 us; speedup 1.0000x reference)
//
#include <hip/hip_runtime.h>

// upfirdn2d: up=2, 4x4 depthwise FIR, pad (2,2), no downsample.
// x: (16,64,128,128) f32, filt: (64,1,4,4) f32, out: (16,64,256,256) f32.
//
// Polyphase: output (oy,ox) reads a 2x2 input neighborhood.
//   oy=2i   -> rows (i-1, K[0][.]), (i,   K[2][.])
//   oy=2i+1 -> rows (i,   K[1][.]), (i+1, K[3][.])
//   ox=2jj   -> cols (jj-1, K[.][0]), (jj,   K[.][2])
//   ox=2jj+1 -> cols (jj,   K[.][1]), (jj+1, K[.][3])
// Out-of-range input == 0 (zero padding).

constexpr int H = 128, W = 128, WO = 256;

__global__ __launch_bounds__(256) void upfirdn2d_up2(
    const float* __restrict__ x, const float* __restrict__ f,
    float* __restrict__ y) {
  const int j  = threadIdx.x;                  // 0..63  -> output cols 4j..4j+3
  const int i  = blockIdx.x * 4 + threadIdx.y; // 0..127 -> output rows 2i, 2i+1
  const int bc = blockIdx.y;                   // 0..1023 (b*64 + c)
  const int c  = bc & 63;

  // 16 filter taps; uniform per block -> scalar loads / SGPRs.
  float k[16];
  const float* kp = f + c * 16;
#pragma unroll
  for (int t = 0; t < 16; ++t) k[t] = kp[t];

  const float* xin = x + (size_t)bc * (H * W);
  float*       yo  = y + (size_t)bc * (WO * WO);

  // Input window: rows i-1..i+1, cols 2j-1..2j+2.
  float r[3][4];
#pragma unroll
  for (int t = 0; t < 3; ++t) {
    const int row = i - 1 + t;
    const bool rok = ((unsigned)row < (unsigned)H);
    const float* rp = xin + row * W;
    float2 mid = rok ? *(const float2*)(rp + 2 * j) : make_float2(0.f, 0.f);
    r[t][0] = (rok && j > 0)  ? rp[2 * j - 1] : 0.f;
    r[t][1] = mid.x;
    r[t][2] = mid.y;
    r[t][3] = (rok && j < 63) ? rp[2 * j + 2] : 0.f;
  }

  // k[fy*4+fx]; row parity 0 uses k[0..3] (row i-1) + k[8..11] (row i),
  // parity 1 uses k[4..7] (row i) + k[12..15] (row i+1).
  float4 o0, o1;
  o0.x = k[0]*r[0][0] + k[2]*r[0][1] + k[8] *r[1][0] + k[10]*r[1][1];
  o0.y = k[1]*r[0][1] + k[3]*r[0][2] + k[9] *r[1][1] + k[11]*r[1][2];
  o0.z = k[0]*r[0][1] + k[2]*r[0][2] + k[8] *r[1][1] + k[10]*r[1][2];
  o0.w = k[1]*r[0][2] + k[3]*r[0][3] + k[9] *r[1][2] + k[11]*r[1][3];

  o1.x = k[4]*r[1][0] + k[6]*r[1][1] + k[12]*r[2][0] + k[14]*r[2][1];
  o1.y = k[5]*r[1][1] + k[7]*r[1][2] + k[13]*r[2][1] + k[15]*r[2][2];
  o1.z = k[4]*r[1][1] + k[6]*r[1][2] + k[12]*r[2][1] + k[14]*r[2][2];
  o1.w = k[5]*r[1][2] + k[7]*r[1][3] + k[13]*r[2][2] + k[15]*r[2][3];

  float4* p0 = (float4*)(yo + (size_t)(2 * i)     * WO + 4 * j);
  float4* p1 = (float4*)(yo + (size_t)(2 * i + 1) * WO + 4 * j);
  *p0 = o0;
  *p1 = o1;
}

extern "C" void kernel_launch(void* const* d_in, const int* in_sizes, int n_in,
                              void* d_out, int out_size, void* d_ws, size_t ws_size,
                              hipStream_t stream) {
  const float* x = (const float*)d_in[0];
  const float* f = (const float*)d_in[1];
  float*       y = (float*)d_out;

  dim3 block(64, 4);   // one wave per output-row-pair; 4 row-pairs per block
  dim3 grid(32, 1024); // 32 * 4 = 128 input rows; 16*64 = 1024 (b,c) planes
  hipLaunchKernelGGL(upfirdn2d_up2, grid, block, 0, stream, x, f, y);
}

// Round 5
// 306.000 us; speedup vs baseline: 1.0777x; 1.0777x over previous
//
#include <hip/hip_runtime.h>

// upfirdn2d: up=2, 4x4 depthwise FIR, pad (2,2), no downsample.
// x: (16,64,128,128) f32, filt: (64,1,4,4) f32, out: (16,64,256,256) f32.
//
// Polyphase (correlation, XLA semantics):
//   out row 2i   = K[0][.]*row(i-1) + K[2][.]*row(i)
//   out row 2i+1 = K[1][.]*row(i)   + K[3][.]*row(i+1)
//   out col 2jj   = K[.][0]*col(jj-1) + K[.][2]*col(jj)
//   out col 2jj+1 = K[.][1]*col(jj)   + K[.][3]*col(jj+1)
// Out-of-range input == 0 (zero padding).
//
// One wave (64 lanes) spans a full 128-col input row; horizontal halo comes
// from __shfl with neighbors, not extra loads. Each thread produces 4 output
// rows x 4 cols from 4 input rows (rows 2q-1..2q+2).

constexpr int H = 128, W = 128, WO = 256;

typedef float vfloat4 __attribute__((ext_vector_type(4)));

__global__ __launch_bounds__(256) void upfirdn2d_up2(
    const float* __restrict__ x, const float* __restrict__ f,
    float* __restrict__ y) {
  const int j  = threadIdx.x;                  // 0..63 -> output cols 4j..4j+3
  const int q  = blockIdx.x * 4 + threadIdx.y; // 0..63 -> output rows 4q..4q+3
  const int bc = blockIdx.y;                   // 0..1023 (b*64 + c)
  const int c  = bc & 63;

  // 16 filter taps; uniform per block -> scalar loads / SGPRs.
  float k[16];
  const float* kp = f + c * 16;
#pragma unroll
  for (int t = 0; t < 16; ++t) k[t] = kp[t];

  const float* xin = x + (size_t)bc * (H * W);
  float*       yo  = y + (size_t)bc * (WO * WO);

  // Input rows 2q-1 .. 2q+2; per row, cols 2j-1, 2j, 2j+1, 2j+2.
  float a[4][4];
#pragma unroll
  for (int t = 0; t < 4; ++t) {
    const int row = 2 * q - 1 + t;
    const bool rok = ((unsigned)row < (unsigned)H);
    float2 mid = rok ? *(const float2*)(xin + row * W + 2 * j)
                     : make_float2(0.f, 0.f);
    const float left  = __shfl_up(mid.y, 1);   // lane j-1's col 2j-1
    const float right = __shfl_down(mid.x, 1); // lane j+1's col 2j+2
    a[t][0] = (j == 0)  ? 0.f : left;
    a[t][1] = mid.x;
    a[t][2] = mid.y;
    a[t][3] = (j == 63) ? 0.f : right;
  }

  // kr = filter row for the upper input row, ks = for the lower input row.
  auto frow = [&](const float* kr, const float (&u)[4],
                  const float* ks, const float (&v)[4]) -> vfloat4 {
    vfloat4 o;
    o.x = kr[0]*u[0] + kr[2]*u[1] + ks[0]*v[0] + ks[2]*v[1];
    o.y = kr[1]*u[1] + kr[3]*u[2] + ks[1]*v[1] + ks[3]*v[2];
    o.z = kr[0]*u[1] + kr[2]*u[2] + ks[0]*v[1] + ks[2]*v[2];
    o.w = kr[1]*u[2] + kr[3]*u[3] + ks[1]*v[2] + ks[3]*v[3];
    return o;
  };

  const vfloat4 o0 = frow(k + 0, a[0], k + 8,  a[1]); // out row 4q   (i=2q)
  const vfloat4 o1 = frow(k + 4, a[1], k + 12, a[2]); // out row 4q+1
  const vfloat4 o2 = frow(k + 0, a[1], k + 8,  a[2]); // out row 4q+2 (i=2q+1)
  const vfloat4 o3 = frow(k + 4, a[2], k + 12, a[3]); // out row 4q+3

  float* base = yo + (size_t)(4 * q) * WO + 4 * j;
  __builtin_nontemporal_store(o0, (vfloat4*)(base));
  __builtin_nontemporal_store(o1, (vfloat4*)(base + WO));
  __builtin_nontemporal_store(o2, (vfloat4*)(base + 2 * WO));
  __builtin_nontemporal_store(o3, (vfloat4*)(base + 3 * WO));
}

extern "C" void kernel_launch(void* const* d_in, const int* in_sizes, int n_in,
                              void* d_out, int out_size, void* d_ws, size_t ws_size,
                              hipStream_t stream) {
  const float* x = (const float*)d_in[0];
  const float* f = (const float*)d_in[1];
  float*       y = (float*)d_out;

  dim3 block(64, 4);   // one wave per 4-output-row strip; 4 strips per block
  dim3 grid(16, 1024); // 16*4 = 64 strips = 256 output rows; 1024 (b,c) planes
  hipLaunchKernelGGL(upfirdn2d_up2, grid, block, 0, stream, x, f, y);
}